// Round 19
// baseline (188.501 us; speedup 1.0000x reference)
//
#include <hip/hip_runtime.h>
#include <hip/hip_bf16.h>
#include <type_traits>

#define DEV __device__ __forceinline__

typedef __attribute__((ext_vector_type(4))) float f32x4;
typedef __attribute__((ext_vector_type(16))) float f32x16;
typedef __attribute__((ext_vector_type(8))) short short8;

static constexpr int Bc = 2, Sc = 2048, HQc = 32, HKVc = 8;

DEV unsigned short f2bf(float f) {
  union { float f; unsigned u; } v; v.f = f;
  unsigned r = v.u + 0x7fffu + ((v.u >> 16) & 1u);
  return (unsigned short)(r >> 16);
}
DEV float bf2f(unsigned short u) {
  union { unsigned u; float f; } v; v.u = ((unsigned)u) << 16;
  return v.f;
}

typedef const unsigned __attribute__((address_space(1)))* gp1;
typedef unsigned __attribute__((address_space(3)))* lp3;
DEV void gload16(const void* g, void* l) {
  __builtin_amdgcn_global_load_lds((gp1)g, (lp3)l, 16, 0, 0);
}

DEV unsigned cvt_pk_bf16(float lo, float hi) {
  unsigned r;
  asm("v_cvt_pk_bf16_f32 %0, %1, %2" : "=v"(r) : "v"(lo), "v"(hi));
  return r;
}
DEV void pl32swap(unsigned& a, unsigned& b) {
  asm("v_permlane32_swap_b32 %0, %1" : "+v"(a), "+v"(b));
}

// ---------------- prep: cast_x + 4x wtrans merged ----------------
__global__ __launch_bounds__(256) void prep(const float* __restrict__ x,
                                            const float* __restrict__ Wq,
                                            const float* __restrict__ Wk,
                                            const float* __restrict__ Wv,
                                            const float* __restrict__ Wo,
                                            unsigned short* __restrict__ xb,
                                            unsigned short* __restrict__ Wqkv,
                                            unsigned short* __restrict__ Wot) {
  __shared__ float t[64][65];
  const int bid = blockIdx.x;
  const int tid = threadIdx.x;
  if (bid < 8192) {
    const size_t i = (size_t)bid * 256 + tid;
    const float4 v = reinterpret_cast<const float4*>(x)[i];
    ushort4 o;
    o.x = f2bf(v.x); o.y = f2bf(v.y); o.z = f2bf(v.z); o.w = f2bf(v.w);
    reinterpret_cast<ushort4*>(xb)[i] = o;
    return;
  }
  const int tbl = bid - 8192;
  const float* in; unsigned short* out; int N, bx, by;
  if (tbl < 1024) { in = Wq; out = Wqkv; N = 2048; bx = tbl & 31; by = tbl >> 5; }
  else if (tbl < 1280) { const int t2 = tbl - 1024; in = Wk; out = Wqkv + (size_t)2048 * 2048; N = 512; bx = t2 & 7; by = t2 >> 3; }
  else if (tbl < 1536) { const int t2 = tbl - 1280; in = Wv; out = Wqkv + (size_t)2560 * 2048; N = 512; bx = t2 & 7; by = t2 >> 3; }
  else { const int t2 = tbl - 1536; in = Wo; out = Wot; N = 2048; bx = t2 & 31; by = t2 >> 5; }
  const int K = 2048;
  const int n0 = bx * 64, k0 = by * 64;
#pragma unroll
  for (int p = 0; p < 4; ++p) {
    const int kr = p * 16 + (tid >> 4);
    const int c = (tid & 15) * 4;
    const float4 v = *reinterpret_cast<const float4*>(&in[(size_t)(k0 + kr) * N + n0 + c]);
    t[c + 0][kr] = v.x; t[c + 1][kr] = v.y; t[c + 2][kr] = v.z; t[c + 3][kr] = v.w;
  }
  __syncthreads();
  const int n = tid >> 2, kc = (tid & 3) * 16;
  union { unsigned short u[16]; uint4 q[2]; } o;
#pragma unroll
  for (int e = 0; e < 16; ++e) o.u[e] = f2bf(t[n][kc + e]);
  uint4* dst = reinterpret_cast<uint4*>(&out[(size_t)(n0 + n) * K + k0 + kc]);
  dst[0] = o.q[0]; dst[1] = o.q[1];
}

// ---------------- GEMM: C(MxN) = A * Bt^T, m97 structure, bijective XCD swizzle ----------------
template <typename CT>
__global__ __launch_bounds__(256) void gemm_bt(const unsigned short* __restrict__ A,
                                               const unsigned short* __restrict__ Bt,
                                               CT* __restrict__ C, int M, int N, int K,
                                               int gx) {
  const int nwg = gridDim.x;
  int bid = blockIdx.x;
  {
    const int qq = nwg >> 3, rr = nwg & 7;
    const int xcd = bid & 7, lid = bid >> 3;
    bid = (xcd < rr ? xcd * (qq + 1) : rr * (qq + 1) + (xcd - rr) * qq) + lid;
  }
  const int m0 = (bid / gx) * 128, n0 = (bid % gx) * 128;
  __shared__ __align__(16) unsigned short As[128 * 64];
  __shared__ __align__(16) unsigned short Bs[128 * 64];
  const int tid = threadIdx.x;
  const int w = tid >> 6, lane = tid & 63;
  const int g = lane >> 4, lm = lane & 15;
  const int wr = w >> 1, wc = w & 1;
  f32x4 acc[4][4] = {};
  const int nk = K >> 6;
  const char* Abase = (const char*)(A + (size_t)m0 * K);
  const char* Bbase = (const char*)(Bt + (size_t)n0 * K);
  const int off = w * 4096 + 16 * lane;
  for (int kt = 0; kt < nk; ++kt) {
    __syncthreads();
#pragma unroll
    for (int i = 0; i < 4; ++i) {
      const int o = off + i * 1024;
      const int row = o >> 7;
      const int kbs = (o & 127) ^ ((row & 7) << 4);
      const size_t gof = (size_t)row * (2 * K) + (size_t)kt * 128 + kbs;
      gload16(Abase + gof, (char*)As + (w * 4096 + i * 1024));
      gload16(Bbase + gof, (char*)Bs + (w * 4096 + i * 1024));
    }
    __syncthreads();
#pragma unroll
    for (int ks = 0; ks < 2; ++ks) {
      short8 af[4], bfr[4];
#pragma unroll
      for (int i = 0; i < 4; ++i) {
        const int ar = wr * 64 + i * 16 + lm;
        af[i] = *reinterpret_cast<const short8*>((const char*)As + ar * 128 + (((ks * 4 + g) ^ (ar & 7)) << 4));
        const int br = wc * 64 + i * 16 + lm;
        bfr[i] = *reinterpret_cast<const short8*>((const char*)Bs + br * 128 + (((ks * 4 + g) ^ (br & 7)) << 4));
      }
#pragma unroll
      for (int i = 0; i < 4; ++i)
#pragma unroll
        for (int j = 0; j < 4; ++j)
          acc[i][j] = __builtin_amdgcn_mfma_f32_16x16x32_bf16(af[i], bfr[j], acc[i][j], 0, 0, 0);
    }
  }
#pragma unroll
  for (int i = 0; i < 4; ++i)
#pragma unroll
    for (int j = 0; j < 4; ++j)
#pragma unroll
      for (int r = 0; r < 4; ++r) {
        const size_t idx = (size_t)(m0 + wr * 64 + i * 16 + g * 4 + r) * N + (n0 + wc * 64 + j * 16 + lm);
        if constexpr (std::is_same<CT, float>::value) C[idx] = acc[i][j][r];
        else C[idx] = (CT)f2bf(acc[i][j][r]);
      }
}

// ---------------- QKV GEMM: 128x96 tiles -> 1024 wg = 4 blocks/CU ----------------
__global__ __launch_bounds__(256) void gemm_qkv96(const unsigned short* __restrict__ A,
                                                  const unsigned short* __restrict__ Bt,
                                                  unsigned short* __restrict__ C) {
  constexpr int K = 2048, N = 3072;
  int bid = blockIdx.x;
  { const int xcd = bid & 7, lid = bid >> 3; bid = xcd * 128 + lid; }  // 1024 % 8 == 0
  const int m0 = (bid >> 5) * 128, n0 = (bid & 31) * 96;
  __shared__ __align__(16) unsigned short As[128 * 64];  // 16KB
  __shared__ __align__(16) unsigned short Bs[96 * 64];   // 12KB
  const int tid = threadIdx.x;
  const int w = tid >> 6, lane = tid & 63;
  const int g = lane >> 4, lm = lane & 15;
  const int wr = w >> 1, wc = w & 1;     // wave tile: 64 rows x 48 cols
  f32x4 acc[4][3] = {};
  const char* Abase = (const char*)(A + (size_t)m0 * K);
  const char* Bbase = (const char*)(Bt + (size_t)n0 * K);
  const int offA = w * 4096 + 16 * lane;
  const int offB = w * 3072 + 16 * lane;
  for (int kt = 0; kt < 32; ++kt) {
    __syncthreads();
#pragma unroll
    for (int i = 0; i < 4; ++i) {
      const int o = offA + i * 1024;
      const int row = o >> 7;
      const int kbs = (o & 127) ^ ((row & 7) << 4);
      gload16(Abase + (size_t)row * (2 * K) + (size_t)kt * 128 + kbs,
              (char*)As + (w * 4096 + i * 1024));
    }
#pragma unroll
    for (int i = 0; i < 3; ++i) {
      const int o = offB + i * 1024;
      const int row = o >> 7;                       // 0..95
      const int kbs = (o & 127) ^ ((row & 7) << 4);
      gload16(Bbase + (size_t)row * (2 * K) + (size_t)kt * 128 + kbs,
              (char*)Bs + (w * 3072 + i * 1024));
    }
    __syncthreads();
#pragma unroll
    for (int ks = 0; ks < 2; ++ks) {
      short8 af[4], bfr[3];
#pragma unroll
      for (int i = 0; i < 4; ++i) {
        const int ar = wr * 64 + i * 16 + lm;
        af[i] = *reinterpret_cast<const short8*>((const char*)As + ar * 128 + (((ks * 4 + g) ^ (ar & 7)) << 4));
      }
#pragma unroll
      for (int j = 0; j < 3; ++j) {
        const int br = wc * 48 + j * 16 + lm;
        bfr[j] = *reinterpret_cast<const short8*>((const char*)Bs + br * 128 + (((ks * 4 + g) ^ (br & 7)) << 4));
      }
#pragma unroll
      for (int i = 0; i < 4; ++i)
#pragma unroll
        for (int j = 0; j < 3; ++j)
          acc[i][j] = __builtin_amdgcn_mfma_f32_16x16x32_bf16(af[i], bfr[j], acc[i][j], 0, 0, 0);
    }
  }
#pragma unroll
  for (int i = 0; i < 4; ++i)
#pragma unroll
    for (int j = 0; j < 3; ++j)
#pragma unroll
      for (int r = 0; r < 4; ++r) {
        const size_t idx = (size_t)(m0 + wr * 64 + i * 16 + g * 4 + r) * N + (n0 + wc * 48 + j * 16 + lm);
        C[idx] = f2bf(acc[i][j][r]);
      }
}

// ---------------- post: ropeK + repack_v ----------------
DEV void rope_body(const unsigned short* __restrict__ Xp, const float* __restrict__ cosT,
                   const float* __restrict__ sinT, unsigned short* __restrict__ Xb,
                   int NH, int colOff, float qs, int bid, int tid) {
  const size_t i = (size_t)bid * 256 + tid;
  const int d = (int)(i & 31);
  const size_t t = i >> 5;
  const int h = (int)(t % NH);
  const size_t row = t / NH;
  const int s = (int)(row & (Sc - 1));
  const size_t b = row >> 11;
  const size_t ib = row * 3072 + colOff + (size_t)h * 64 + d;
  const float q1 = bf2f(Xp[ib]);
  const float q2 = bf2f(Xp[ib + 32]);
  const float c = cosT[s * 64 + d], sn = sinT[s * 64 + d];
  const size_t ob = ((b * NH + h) * (size_t)Sc + s) * 64 + d;
  Xb[ob] = f2bf((q1 * c - q2 * sn) * qs);
  Xb[ob + 32] = f2bf((q2 * c + q1 * sn) * qs);
}

__global__ __launch_bounds__(256) void post(const unsigned short* __restrict__ QKVp,
                                            const float* __restrict__ cosT,
                                            const float* __restrict__ sinT,
                                            unsigned short* __restrict__ Kbf,
                                            unsigned short* __restrict__ Vtb) {
  __shared__ int t[64][65];
  const int bid = blockIdx.x;
  const int tid = threadIdx.x;
  if (bid < 4096) {
    rope_body(QKVp, cosT, sinT, Kbf, HKVc, 2048, 1.0f, bid, tid);
    return;
  }
  const int tv = bid - 4096;
  const int bh = tv >> 5;
  const int s0 = (tv & 31) * 64;
  const int b = bh >> 3, hk = bh & 7;
#pragma unroll
  for (int p = 0; p < 2; ++p) {
    const int sr = p * 32 + (tid >> 3);
    const int c = (tid & 7) * 8;
    short8 v = *reinterpret_cast<const short8*>(&QKVp[(size_t)(b * Sc + s0 + sr) * 3072 + 2560 + hk * 64 + c]);
#pragma unroll
    for (int e = 0; e < 8; ++e) t[c + e][sr] = (unsigned short)v[e];
  }
  __syncthreads();
  const int d = tid >> 2, scol = (tid & 3) * 16;
  union { unsigned short u[16]; uint4 q[2]; } o;
#pragma unroll
  for (int e = 0; e < 16; ++e) o.u[e] = (unsigned short)t[d][scol + e];
  uint4* dst = reinterpret_cast<uint4*>(&Vtb[((size_t)bh * 64 + d) * Sc + s0 + scol]);
  dst[0] = o.q[0]; dst[1] = o.q[1];
}

// ---------------- causal GQA flash attention: r17 structure + counted-vmcnt dbuf (T4, r14-audited) ----
__global__ __launch_bounds__(256, 4) void attn_fwd(const unsigned short* __restrict__ QKVp,
                                                   const unsigned short* __restrict__ Kb,
                                                   const unsigned short* __restrict__ Vt,
                                                   const float* __restrict__ cosT,
                                                   const float* __restrict__ sinT,
                                                   unsigned short* __restrict__ Ob) {
  __shared__ __align__(16) char sm[32768];
  const int tid = threadIdx.x;
  const int w = tid >> 6, lane = tid & 63;
  const int lane31 = lane & 31, hi = lane >> 5;
  const int hi16 = hi * 16;
  const int hl = w >> 1, wh = w & 1;
  const int bid = blockIdx.x;
  const int hk = bid & 7;
  const int sub = (bid >> 3) & 3;
  const int tq = (bid >> 5) & 7;
  const int quarter = bid >> 8;
  int qt;
  if (quarter == 0) qt = 31 - tq;
  else if (quarter == 1) qt = 16 + tq;
  else if (quarter == 2) qt = 15 - tq;
  else qt = tq;
  const int b = sub >> 1, hp = sub & 1;
  const int h = hk * 4 + hp * 2 + hl;
  const int q0 = qt * 64;
  const char* Kbase = (const char*)(Kb + (size_t)(b * HKVc + hk) * Sc * 64);
  const char* Vbase = (const char*)(Vt + (size_t)(b * HKVc + hk) * 64 * Sc);
  // ---- Q load from QKVp + in-register RoPE ----
  const int srow = q0 + wh * 32 + lane31;
  const unsigned short* Qraw = QKVp + ((size_t)(b * Sc) + srow) * 3072 + h * 64;
  short8 qraw[4];
#pragma unroll
  for (int c = 0; c < 4; ++c)
    qraw[c] = *reinterpret_cast<const short8*>(Qraw + c * 16 + hi * 8);
  const float* cbp = cosT + (size_t)srow * 64;
  const float* sbp = sinT + (size_t)srow * 64;
  const float qs = 0.125f * 1.44269504089f;
  short8 qf[4];
#pragma unroll
  for (int c = 0; c < 4; ++c) {
    short8 o;
#pragma unroll
    for (int e = 0; e < 8; ++e) {
      const int d = c * 16 + hi * 8 + e;
      const float v = bf2f((unsigned short)qraw[c][e]);
      const float p = bf2f((unsigned short)qraw[c ^ 2][e]);
      const float sgn = (d < 32) ? -1.f : 1.f;
      o[e] = (short)f2bf((v * cbp[d] + sgn * p * sbp[d]) * qs);
    }
    qf[c] = o;
  }

  f32x16 acc[2] = {};
  f32x16 accl = {};
  const int qlocal = wh * 32 + lane31 - 4 * hi;
  union { unsigned u[4]; short8 s; } onesu;
  onesu.u[0] = onesu.u[1] = onesu.u[2] = onesu.u[3] = 0x3f803f80u;
  const short8 ones8 = onesu.s;

  const int so0 = tid * 16;
  auto stage = [&](int kt, int buf) {
    char* Kd = sm + buf * 16384;
    char* Vd = sm + buf * 16384 + 8192;
#pragma unroll
    for (int q = 0; q < 2; ++q) {
      const int o = q * 4096 + so0;
      const int srw = o >> 7;
      const int kbs = (o & 127) ^ ((srw & 7) << 4);
      const int ld = q * 4096 + w * 1024;
      gload16(Kbase + (size_t)(kt * 64 + srw) * 128 + kbs, Kd + ld);
      gload16(Vbase + (size_t)srw * (Sc * 2) + (size_t)kt * 128 + kbs, Vd + ld);
    }
  };

  stage(0, 0);
  for (int kt = 0; kt <= qt; ++kt) {
    const int cur = kt & 1;
    __builtin_amdgcn_s_barrier();             // all waves done reading buf[cur^1]
    if (kt < qt) {
      stage(kt + 1, cur ^ 1);
      asm volatile("s_waitcnt vmcnt(4)" ::: "memory");   // stage(kt) landed (own 4 loads)
    } else {
      asm volatile("s_waitcnt vmcnt(0)" ::: "memory");
    }
    __builtin_amdgcn_sched_barrier(0);
    __builtin_amdgcn_s_barrier();             // all waves' stage(kt) visible
    const char* Kbuf = sm + cur * 16384;
    const char* Vbuf = sm + cur * 16384 + 8192;
    const bool dg = (kt == qt);
    const bool do_hi = !dg || (wh == 1);
    short8 pf[4];
    {
      f32x16 st = {};
      __builtin_amdgcn_s_setprio(1);
#pragma unroll
      for (int c = 0; c < 4; ++c) {
        const int row = lane31;
        const short8 kf = *reinterpret_cast<const short8*>(Kbuf + row * 128 + ((c * 32 + hi16) ^ ((row & 7) << 4)));
        st = __builtin_amdgcn_mfma_f32_32x32x16_bf16(kf, qf[c], st, 0, 0, 0);
      }
      __builtin_amdgcn_s_setprio(0);
      if (dg && wh == 0) {
#pragma unroll
        for (int rr = 0; rr < 16; ++rr) {
          const int kl = (rr & 3) + 8 * (rr >> 2);
          st[rr] = exp2f(kl > qlocal ? -1e30f : st[rr]);
        }
      } else {
#pragma unroll
        for (int rr = 0; rr < 16; ++rr) st[rr] = exp2f(st[rr]);
      }
      union { unsigned u[4]; short8 s; } x, y;
      unsigned a0 = cvt_pk_bf16(st[0], st[1]), b0 = cvt_pk_bf16(st[4], st[5]);
      pl32swap(a0, b0);
      unsigned a1 = cvt_pk_bf16(st[2], st[3]), b1 = cvt_pk_bf16(st[6], st[7]);
      pl32swap(a1, b1);
      x.u[0] = a0; x.u[1] = a1; x.u[2] = b0; x.u[3] = b1; pf[0] = x.s;
      unsigned a2 = cvt_pk_bf16(st[8], st[9]), b2 = cvt_pk_bf16(st[12], st[13]);
      pl32swap(a2, b2);
      unsigned a3 = cvt_pk_bf16(st[10], st[11]), b3 = cvt_pk_bf16(st[14], st[15]);
      pl32swap(a3, b3);
      y.u[0] = a2; y.u[1] = a3; y.u[2] = b2; y.u[3] = b3; pf[1] = y.s;
    }
    if (do_hi) {
      f32x16 st = {};
      __builtin_amdgcn_s_setprio(1);
#pragma unroll
      for (int c = 0; c < 4; ++c) {
        const int row = 32 + lane31;
        const short8 kf = *reinterpret_cast<const short8*>(Kbuf + row * 128 + ((c * 32 + hi16) ^ ((row & 7) << 4)));
        st = __builtin_amdgcn_mfma_f32_32x32x16_bf16(kf, qf[c], st, 0, 0, 0);
      }
      __builtin_amdgcn_s_setprio(0);
      if (dg) {
        const int rhs = qlocal - 32;
#pragma unroll
        for (int rr = 0; rr < 16; ++rr) {
          const int kl = (rr & 3) + 8 * (rr >> 2);
          st[rr] = exp2f(kl > rhs ? -1e30f : st[rr]);
        }
      } else {
#pragma unroll
        for (int rr = 0; rr < 16; ++rr) st[rr] = exp2f(st[rr]);
      }
      union { unsigned u[4]; short8 s; } x, y;
      unsigned a0 = cvt_pk_bf16(st[0], st[1]), b0 = cvt_pk_bf16(st[4], st[5]);
      pl32swap(a0, b0);
      unsigned a1 = cvt_pk_bf16(st[2], st[3]), b1 = cvt_pk_bf16(st[6], st[7]);
      pl32swap(a1, b1);
      x.u[0] = a0; x.u[1] = a1; x.u[2] = b0; x.u[3] = b1; pf[2] = x.s;
      unsigned a2 = cvt_pk_bf16(st[8], st[9]), b2 = cvt_pk_bf16(st[12], st[13]);
      pl32swap(a2, b2);
      unsigned a3 = cvt_pk_bf16(st[10], st[11]), b3 = cvt_pk_bf16(st[14], st[15]);
      pl32swap(a3, b3);
      y.u[0] = a2; y.u[1] = a3; y.u[2] = b2; y.u[3] = b3; pf[3] = y.s;
    }
    __builtin_amdgcn_s_setprio(1);
#pragma unroll
    for (int dt = 0; dt < 2; ++dt) {
      const int row = dt * 32 + lane31;
      const int rx = (row & 7) << 4;
#pragma unroll
      for (int c = 0; c < 2; ++c) {
        const short8 vf = *reinterpret_cast<const short8*>(Vbuf + row * 128 + ((c * 32 + hi16) ^ rx));
        acc[dt] = __builtin_amdgcn_mfma_f32_32x32x16_bf16(pf[c], vf, acc[dt], 0, 0, 0);
      }
      if (do_hi) {
#pragma unroll
        for (int c = 2; c < 4; ++c) {
          const short8 vf = *reinterpret_cast<const short8*>(Vbuf + row * 128 + ((c * 32 + hi16) ^ rx));
          acc[dt] = __builtin_amdgcn_mfma_f32_32x32x16_bf16(pf[c], vf, acc[dt], 0, 0, 0);
        }
      }
    }
    accl = __builtin_amdgcn_mfma_f32_32x32x16_bf16(pf[0], ones8, accl, 0, 0, 0);
    accl = __builtin_amdgcn_mfma_f32_32x32x16_bf16(pf[1], ones8, accl, 0, 0, 0);
    if (do_hi) {
      accl = __builtin_amdgcn_mfma_f32_32x32x16_bf16(pf[2], ones8, accl, 0, 0, 0);
      accl = __builtin_amdgcn_mfma_f32_32x32x16_bf16(pf[3], ones8, accl, 0, 0, 0);
    }
    __builtin_amdgcn_s_setprio(0);
  }
  __syncthreads();   // all waves done with K/V buffers before Os reuse
  unsigned short* Os = (unsigned short*)sm;
#pragma unroll
  for (int rr = 0; rr < 16; ++rr) {
    const int cr = (rr & 3) + 8 * (rr >> 2) + 4 * hi;
    const float inv = 1.f / accl[rr];
    const int row = wh * 32 + cr;
#pragma unroll
    for (int dt = 0; dt < 2; ++dt)
      Os[row * 128 + hl * 64 + dt * 32 + lane31] = f2bf(acc[dt][rr] * inv);
  }
  __syncthreads();
  unsigned short* Op = Ob + (size_t)(b * Sc + q0) * (HQc * 64) + (hk * 4 + hp * 2) * 64;
#pragma unroll
  for (int i = 0; i < 4; ++i) {
    const int cid = i * 256 + tid;
    const int row = cid >> 4;
    const int cb = (cid & 15) * 16;
    const uint4 v = *reinterpret_cast<const uint4*>(sm + row * 256 + cb);
    *reinterpret_cast<uint4*>((char*)(Op + (size_t)row * (HQc * 64)) + cb) = v;
  }
}

extern "C" void kernel_launch(void* const* d_in, const int* in_sizes, int n_in,
                              void* d_out, int out_size, void* d_ws, size_t ws_size,
                              hipStream_t stream) {
  (void)in_sizes; (void)n_in; (void)out_size; (void)ws_size;
  const float* x    = (const float*)d_in[0];
  const float* cosT = (const float*)d_in[1];
  const float* sinT = (const float*)d_in[2];
  // d_in[3] = mask: deterministic causal, not read
  const float* Wq = (const float*)d_in[4];
  const float* Wk = (const float*)d_in[5];
  const float* Wv = (const float*)d_in[6];
  const float* Wo = (const float*)d_in[7];
  float* out = (float*)d_out;
  char* ws = (char*)d_ws;
  const size_t MB = (size_t)1 << 20;
  unsigned short* xb   = (unsigned short*)(ws + 0 * MB);   // 16MB (x bf16; reused as Att)
  unsigned short* Wqkv = (unsigned short*)(ws + 16 * MB);  // 12MB [3072][2048]
  unsigned short* Wot  = (unsigned short*)(ws + 28 * MB);  // 8MB
  unsigned short* Kbf  = (unsigned short*)(ws + 36 * MB);  // 4MB
  unsigned short* Vtb  = (unsigned short*)(ws + 40 * MB);  // 4MB
  unsigned short* Att  = (unsigned short*)(ws + 0 * MB);   // reuse xb (dead after QKV GEMM)
  unsigned short* QKVp = (unsigned short*)d_out;           // 24MB in d_out (dead before O-proj)

  prep<<<10752, 256, 0, stream>>>(x, Wq, Wk, Wv, Wo, xb, Wqkv, Wot);
  gemm_qkv96<<<1024, 256, 0, stream>>>(xb, Wqkv, QKVp);
  post<<<4608, 256, 0, stream>>>(QKVp, cosT, sinT, Kbf, Vtb);
  attn_fwd<<<1024, 256, 0, stream>>>(QKVp, Kbf, Vtb, cosT, sinT, Att);
  gemm_bt<float><<<512, 256, 0, stream>>>(Att, Wot, out, 4096, 2048, 2048, 16);
}

// Round 20
// 187.393 us; speedup vs baseline: 1.0059x; 1.0059x over previous
//
#include <hip/hip_runtime.h>
#include <hip/hip_bf16.h>
#include <type_traits>

#define DEV __device__ __forceinline__

typedef __attribute__((ext_vector_type(4))) float f32x4;
typedef __attribute__((ext_vector_type(16))) float f32x16;
typedef __attribute__((ext_vector_type(8))) short short8;

static constexpr int Bc = 2, Sc = 2048, HQc = 32, HKVc = 8;

DEV unsigned short f2bf(float f) {
  union { float f; unsigned u; } v; v.f = f;
  unsigned r = v.u + 0x7fffu + ((v.u >> 16) & 1u);
  return (unsigned short)(r >> 16);
}
DEV float bf2f(unsigned short u) {
  union { unsigned u; float f; } v; v.u = ((unsigned)u) << 16;
  return v.f;
}

typedef const unsigned __attribute__((address_space(1)))* gp1;
typedef unsigned __attribute__((address_space(3)))* lp3;
DEV void gload16(const void* g, void* l) {
  __builtin_amdgcn_global_load_lds((gp1)g, (lp3)l, 16, 0, 0);
}

DEV unsigned cvt_pk_bf16(float lo, float hi) {
  unsigned r;
  asm("v_cvt_pk_bf16_f32 %0, %1, %2" : "=v"(r) : "v"(lo), "v"(hi));
  return r;
}
DEV void pl32swap(unsigned& a, unsigned& b) {
  asm("v_permlane32_swap_b32 %0, %1" : "+v"(a), "+v"(b));
}

// ---------------- prep: cast_x + 4x wtrans merged ----------------
__global__ __launch_bounds__(256) void prep(const float* __restrict__ x,
                                            const float* __restrict__ Wq,
                                            const float* __restrict__ Wk,
                                            const float* __restrict__ Wv,
                                            const float* __restrict__ Wo,
                                            unsigned short* __restrict__ xb,
                                            unsigned short* __restrict__ Wqkv,
                                            unsigned short* __restrict__ Wot) {
  __shared__ float t[64][65];
  const int bid = blockIdx.x;
  const int tid = threadIdx.x;
  if (bid < 8192) {
    const size_t i = (size_t)bid * 256 + tid;
    const float4 v = reinterpret_cast<const float4*>(x)[i];
    ushort4 o;
    o.x = f2bf(v.x); o.y = f2bf(v.y); o.z = f2bf(v.z); o.w = f2bf(v.w);
    reinterpret_cast<ushort4*>(xb)[i] = o;
    return;
  }
  const int tbl = bid - 8192;
  const float* in; unsigned short* out; int N, bx, by;
  if (tbl < 1024) { in = Wq; out = Wqkv; N = 2048; bx = tbl & 31; by = tbl >> 5; }
  else if (tbl < 1280) { const int t2 = tbl - 1024; in = Wk; out = Wqkv + (size_t)2048 * 2048; N = 512; bx = t2 & 7; by = t2 >> 3; }
  else if (tbl < 1536) { const int t2 = tbl - 1280; in = Wv; out = Wqkv + (size_t)2560 * 2048; N = 512; bx = t2 & 7; by = t2 >> 3; }
  else { const int t2 = tbl - 1536; in = Wo; out = Wot; N = 2048; bx = t2 & 31; by = t2 >> 5; }
  const int K = 2048;
  const int n0 = bx * 64, k0 = by * 64;
#pragma unroll
  for (int p = 0; p < 4; ++p) {
    const int kr = p * 16 + (tid >> 4);
    const int c = (tid & 15) * 4;
    const float4 v = *reinterpret_cast<const float4*>(&in[(size_t)(k0 + kr) * N + n0 + c]);
    t[c + 0][kr] = v.x; t[c + 1][kr] = v.y; t[c + 2][kr] = v.z; t[c + 3][kr] = v.w;
  }
  __syncthreads();
  const int n = tid >> 2, kc = (tid & 3) * 16;
  union { unsigned short u[16]; uint4 q[2]; } o;
#pragma unroll
  for (int e = 0; e < 16; ++e) o.u[e] = f2bf(t[n][kc + e]);
  uint4* dst = reinterpret_cast<uint4*>(&out[(size_t)(n0 + n) * K + k0 + kc]);
  dst[0] = o.q[0]; dst[1] = o.q[1];
}

// ---------------- QKV GEMM: 128x96 tiles -> 1024 wg = 4 blocks/CU ----------------
__global__ __launch_bounds__(256) void gemm_qkv96(const unsigned short* __restrict__ A,
                                                  const unsigned short* __restrict__ Bt,
                                                  unsigned short* __restrict__ C) {
  constexpr int K = 2048, N = 3072;
  int bid = blockIdx.x;
  { const int xcd = bid & 7, lid = bid >> 3; bid = xcd * 128 + lid; }  // 1024 % 8 == 0
  const int m0 = (bid >> 5) * 128, n0 = (bid & 31) * 96;
  __shared__ __align__(16) unsigned short As[128 * 64];  // 16KB
  __shared__ __align__(16) unsigned short Bs[96 * 64];   // 12KB
  const int tid = threadIdx.x;
  const int w = tid >> 6, lane = tid & 63;
  const int g = lane >> 4, lm = lane & 15;
  const int wr = w >> 1, wc = w & 1;     // wave tile: 64 rows x 48 cols
  f32x4 acc[4][3] = {};
  const char* Abase = (const char*)(A + (size_t)m0 * K);
  const char* Bbase = (const char*)(Bt + (size_t)n0 * K);
  const int offA = w * 4096 + 16 * lane;
  const int offB = w * 3072 + 16 * lane;
  for (int kt = 0; kt < 32; ++kt) {
    __syncthreads();
#pragma unroll
    for (int i = 0; i < 4; ++i) {
      const int o = offA + i * 1024;
      const int row = o >> 7;
      const int kbs = (o & 127) ^ ((row & 7) << 4);
      gload16(Abase + (size_t)row * (2 * K) + (size_t)kt * 128 + kbs,
              (char*)As + (w * 4096 + i * 1024));
    }
#pragma unroll
    for (int i = 0; i < 3; ++i) {
      const int o = offB + i * 1024;
      const int row = o >> 7;                       // 0..95
      const int kbs = (o & 127) ^ ((row & 7) << 4);
      gload16(Bbase + (size_t)row * (2 * K) + (size_t)kt * 128 + kbs,
              (char*)Bs + (w * 3072 + i * 1024));
    }
    __syncthreads();
#pragma unroll
    for (int ks = 0; ks < 2; ++ks) {
      short8 af[4], bfr[3];
#pragma unroll
      for (int i = 0; i < 4; ++i) {
        const int ar = wr * 64 + i * 16 + lm;
        af[i] = *reinterpret_cast<const short8*>((const char*)As + ar * 128 + (((ks * 4 + g) ^ (ar & 7)) << 4));
      }
#pragma unroll
      for (int j = 0; j < 3; ++j) {
        const int br = wc * 48 + j * 16 + lm;
        bfr[j] = *reinterpret_cast<const short8*>((const char*)Bs + br * 128 + (((ks * 4 + g) ^ (br & 7)) << 4));
      }
#pragma unroll
      for (int i = 0; i < 4; ++i)
#pragma unroll
        for (int j = 0; j < 3; ++j)
          acc[i][j] = __builtin_amdgcn_mfma_f32_16x16x32_bf16(af[i], bfr[j], acc[i][j], 0, 0, 0);
    }
  }
#pragma unroll
  for (int i = 0; i < 4; ++i)
#pragma unroll
    for (int j = 0; j < 3; ++j)
#pragma unroll
      for (int r = 0; r < 4; ++r) {
        const size_t idx = (size_t)(m0 + wr * 64 + i * 16 + g * 4 + r) * N + (n0 + wc * 48 + j * 16 + lm);
        C[idx] = f2bf(acc[i][j][r]);
      }
}

// ---------------- O-proj GEMM: 64x128 tiles -> 1024 wg = 4 blocks/CU ----------------
// out[4096][2048] f32 = Att * Wot^T. Same K-order/values as 128^2 version (bitwise identical).
__global__ __launch_bounds__(256) void gemm_o64(const unsigned short* __restrict__ A,
                                                const unsigned short* __restrict__ Bt,
                                                float* __restrict__ C) {
  constexpr int K = 2048, N = 2048;
  int bid = blockIdx.x;
  { const int xcd = bid & 7, lid = bid >> 3; bid = xcd * 128 + lid; }  // 1024 % 8 == 0
  const int m0 = (bid >> 4) * 64, n0 = (bid & 15) * 128;
  __shared__ __align__(16) unsigned short As[64 * 64];    // 8KB
  __shared__ __align__(16) unsigned short Bs[128 * 64];   // 16KB
  const int tid = threadIdx.x;
  const int w = tid >> 6, lane = tid & 63;
  const int g = lane >> 4, lm = lane & 15;
  const int wr = w >> 1, wc = w & 1;     // wave tile: 32 rows x 64 cols
  f32x4 acc[2][4] = {};
  const char* Abase = (const char*)(A + (size_t)m0 * K);
  const char* Bbase = (const char*)(Bt + (size_t)n0 * K);
  for (int kt = 0; kt < 32; ++kt) {
    __syncthreads();
#pragma unroll
    for (int i = 0; i < 2; ++i) {
      const int o = i * 4096 + tid * 16;
      const int row = o >> 7;                       // 0..63
      const int kbs = (o & 127) ^ ((row & 7) << 4);
      gload16(Abase + (size_t)row * (2 * K) + (size_t)kt * 128 + kbs,
              (char*)As + (i * 4096 + w * 1024));
    }
#pragma unroll
    for (int i = 0; i < 4; ++i) {
      const int o = i * 4096 + tid * 16;
      const int row = o >> 7;                       // 0..127
      const int kbs = (o & 127) ^ ((row & 7) << 4);
      gload16(Bbase + (size_t)row * (2 * K) + (size_t)kt * 128 + kbs,
              (char*)Bs + (i * 4096 + w * 1024));
    }
    __syncthreads();
#pragma unroll
    for (int ks = 0; ks < 2; ++ks) {
      short8 af[2], bfr[4];
#pragma unroll
      for (int i = 0; i < 2; ++i) {
        const int ar = wr * 32 + i * 16 + lm;
        af[i] = *reinterpret_cast<const short8*>((const char*)As + ar * 128 + (((ks * 4 + g) ^ (ar & 7)) << 4));
      }
#pragma unroll
      for (int j = 0; j < 4; ++j) {
        const int br = wc * 64 + j * 16 + lm;
        bfr[j] = *reinterpret_cast<const short8*>((const char*)Bs + br * 128 + (((ks * 4 + g) ^ (br & 7)) << 4));
      }
#pragma unroll
      for (int i = 0; i < 2; ++i)
#pragma unroll
        for (int j = 0; j < 4; ++j)
          acc[i][j] = __builtin_amdgcn_mfma_f32_16x16x32_bf16(af[i], bfr[j], acc[i][j], 0, 0, 0);
    }
  }
#pragma unroll
  for (int i = 0; i < 2; ++i)
#pragma unroll
    for (int j = 0; j < 4; ++j)
#pragma unroll
      for (int r = 0; r < 4; ++r) {
        const size_t idx = (size_t)(m0 + wr * 32 + i * 16 + g * 4 + r) * N + (n0 + wc * 64 + j * 16 + lm);
        C[idx] = acc[i][j][r];
      }
}

// ---------------- post: ropeK + repack_v ----------------
DEV void rope_body(const unsigned short* __restrict__ Xp, const float* __restrict__ cosT,
                   const float* __restrict__ sinT, unsigned short* __restrict__ Xb,
                   int NH, int colOff, float qs, int bid, int tid) {
  const size_t i = (size_t)bid * 256 + tid;
  const int d = (int)(i & 31);
  const size_t t = i >> 5;
  const int h = (int)(t % NH);
  const size_t row = t / NH;
  const int s = (int)(row & (Sc - 1));
  const size_t b = row >> 11;
  const size_t ib = row * 3072 + colOff + (size_t)h * 64 + d;
  const float q1 = bf2f(Xp[ib]);
  const float q2 = bf2f(Xp[ib + 32]);
  const float c = cosT[s * 64 + d], sn = sinT[s * 64 + d];
  const size_t ob = ((b * NH + h) * (size_t)Sc + s) * 64 + d;
  Xb[ob] = f2bf((q1 * c - q2 * sn) * qs);
  Xb[ob + 32] = f2bf((q2 * c + q1 * sn) * qs);
}

__global__ __launch_bounds__(256) void post(const unsigned short* __restrict__ QKVp,
                                            const float* __restrict__ cosT,
                                            const float* __restrict__ sinT,
                                            unsigned short* __restrict__ Kbf,
                                            unsigned short* __restrict__ Vtb) {
  __shared__ int t[64][65];
  const int bid = blockIdx.x;
  const int tid = threadIdx.x;
  if (bid < 4096) {
    rope_body(QKVp, cosT, sinT, Kbf, HKVc, 2048, 1.0f, bid, tid);
    return;
  }
  const int tv = bid - 4096;
  const int bh = tv >> 5;
  const int s0 = (tv & 31) * 64;
  const int b = bh >> 3, hk = bh & 7;
#pragma unroll
  for (int p = 0; p < 2; ++p) {
    const int sr = p * 32 + (tid >> 3);
    const int c = (tid & 7) * 8;
    short8 v = *reinterpret_cast<const short8*>(&QKVp[(size_t)(b * Sc + s0 + sr) * 3072 + 2560 + hk * 64 + c]);
#pragma unroll
    for (int e = 0; e < 8; ++e) t[c + e][sr] = (unsigned short)v[e];
  }
  __syncthreads();
  const int d = tid >> 2, scol = (tid & 3) * 16;
  union { unsigned short u[16]; uint4 q[2]; } o;
#pragma unroll
  for (int e = 0; e < 16; ++e) o.u[e] = (unsigned short)t[d][scol + e];
  uint4* dst = reinterpret_cast<uint4*>(&Vtb[((size_t)bh * 64 + d) * Sc + s0 + scol]);
  dst[0] = o.q[0]; dst[1] = o.q[1];
}

// ---------------- causal GQA flash attention (r19: counted-vmcnt, inline Q-RoPE) ----------------
__global__ __launch_bounds__(256, 4) void attn_fwd(const unsigned short* __restrict__ QKVp,
                                                   const unsigned short* __restrict__ Kb,
                                                   const unsigned short* __restrict__ Vt,
                                                   const float* __restrict__ cosT,
                                                   const float* __restrict__ sinT,
                                                   unsigned short* __restrict__ Ob) {
  __shared__ __align__(16) char sm[32768];
  const int tid = threadIdx.x;
  const int w = tid >> 6, lane = tid & 63;
  const int lane31 = lane & 31, hi = lane >> 5;
  const int hi16 = hi * 16;
  const int hl = w >> 1, wh = w & 1;
  const int bid = blockIdx.x;
  const int hk = bid & 7;
  const int sub = (bid >> 3) & 3;
  const int tq = (bid >> 5) & 7;
  const int quarter = bid >> 8;
  int qt;
  if (quarter == 0) qt = 31 - tq;
  else if (quarter == 1) qt = 16 + tq;
  else if (quarter == 2) qt = 15 - tq;
  else qt = tq;
  const int b = sub >> 1, hp = sub & 1;
  const int h = hk * 4 + hp * 2 + hl;
  const int q0 = qt * 64;
  const char* Kbase = (const char*)(Kb + (size_t)(b * HKVc + hk) * Sc * 64);
  const char* Vbase = (const char*)(Vt + (size_t)(b * HKVc + hk) * 64 * Sc);
  const int srow = q0 + wh * 32 + lane31;
  const unsigned short* Qraw = QKVp + ((size_t)(b * Sc) + srow) * 3072 + h * 64;
  short8 qraw[4];
#pragma unroll
  for (int c = 0; c < 4; ++c)
    qraw[c] = *reinterpret_cast<const short8*>(Qraw + c * 16 + hi * 8);
  const float* cbp = cosT + (size_t)srow * 64;
  const float* sbp = sinT + (size_t)srow * 64;
  const float qs = 0.125f * 1.44269504089f;
  short8 qf[4];
#pragma unroll
  for (int c = 0; c < 4; ++c) {
    short8 o;
#pragma unroll
    for (int e = 0; e < 8; ++e) {
      const int d = c * 16 + hi * 8 + e;
      const float v = bf2f((unsigned short)qraw[c][e]);
      const float p = bf2f((unsigned short)qraw[c ^ 2][e]);
      const float sgn = (d < 32) ? -1.f : 1.f;
      o[e] = (short)f2bf((v * cbp[d] + sgn * p * sbp[d]) * qs);
    }
    qf[c] = o;
  }

  f32x16 acc[2] = {};
  f32x16 accl = {};
  const int qlocal = wh * 32 + lane31 - 4 * hi;
  union { unsigned u[4]; short8 s; } onesu;
  onesu.u[0] = onesu.u[1] = onesu.u[2] = onesu.u[3] = 0x3f803f80u;
  const short8 ones8 = onesu.s;

  const int so0 = tid * 16;
  auto stage = [&](int kt, int buf) {
    char* Kd = sm + buf * 16384;
    char* Vd = sm + buf * 16384 + 8192;
#pragma unroll
    for (int q = 0; q < 2; ++q) {
      const int o = q * 4096 + so0;
      const int srw = o >> 7;
      const int kbs = (o & 127) ^ ((srw & 7) << 4);
      const int ld = q * 4096 + w * 1024;
      gload16(Kbase + (size_t)(kt * 64 + srw) * 128 + kbs, Kd + ld);
      gload16(Vbase + (size_t)srw * (Sc * 2) + (size_t)kt * 128 + kbs, Vd + ld);
    }
  };

  stage(0, 0);
  for (int kt = 0; kt <= qt; ++kt) {
    const int cur = kt & 1;
    __builtin_amdgcn_s_barrier();
    if (kt < qt) {
      stage(kt + 1, cur ^ 1);
      asm volatile("s_waitcnt vmcnt(4)" ::: "memory");
    } else {
      asm volatile("s_waitcnt vmcnt(0)" ::: "memory");
    }
    __builtin_amdgcn_sched_barrier(0);
    __builtin_amdgcn_s_barrier();
    const char* Kbuf = sm + cur * 16384;
    const char* Vbuf = sm + cur * 16384 + 8192;
    const bool dg = (kt == qt);
    const bool do_hi = !dg || (wh == 1);
    short8 pf[4];
    {
      f32x16 st = {};
      __builtin_amdgcn_s_setprio(1);
#pragma unroll
      for (int c = 0; c < 4; ++c) {
        const int row = lane31;
        const short8 kf = *reinterpret_cast<const short8*>(Kbuf + row * 128 + ((c * 32 + hi16) ^ ((row & 7) << 4)));
        st = __builtin_amdgcn_mfma_f32_32x32x16_bf16(kf, qf[c], st, 0, 0, 0);
      }
      __builtin_amdgcn_s_setprio(0);
      if (dg && wh == 0) {
#pragma unroll
        for (int rr = 0; rr < 16; ++rr) {
          const int kl = (rr & 3) + 8 * (rr >> 2);
          st[rr] = exp2f(kl > qlocal ? -1e30f : st[rr]);
        }
      } else {
#pragma unroll
        for (int rr = 0; rr < 16; ++rr) st[rr] = exp2f(st[rr]);
      }
      union { unsigned u[4]; short8 s; } x, y;
      unsigned a0 = cvt_pk_bf16(st[0], st[1]), b0 = cvt_pk_bf16(st[4], st[5]);
      pl32swap(a0, b0);
      unsigned a1 = cvt_pk_bf16(st[2], st[3]), b1 = cvt_pk_bf16(st[6], st[7]);
      pl32swap(a1, b1);
      x.u[0] = a0; x.u[1] = a1; x.u[2] = b0; x.u[3] = b1; pf[0] = x.s;
      unsigned a2 = cvt_pk_bf16(st[8], st[9]), b2 = cvt_pk_bf16(st[12], st[13]);
      pl32swap(a2, b2);
      unsigned a3 = cvt_pk_bf16(st[10], st[11]), b3 = cvt_pk_bf16(st[14], st[15]);
      pl32swap(a3, b3);
      y.u[0] = a2; y.u[1] = a3; y.u[2] = b2; y.u[3] = b3; pf[1] = y.s;
    }
    if (do_hi) {
      f32x16 st = {};
      __builtin_amdgcn_s_setprio(1);
#pragma unroll
      for (int c = 0; c < 4; ++c) {
        const int row = 32 + lane31;
        const short8 kf = *reinterpret_cast<const short8*>(Kbuf + row * 128 + ((c * 32 + hi16) ^ ((row & 7) << 4)));
        st = __builtin_amdgcn_mfma_f32_32x32x16_bf16(kf, qf[c], st, 0, 0, 0);
      }
      __builtin_amdgcn_s_setprio(0);
      if (dg) {
        const int rhs = qlocal - 32;
#pragma unroll
        for (int rr = 0; rr < 16; ++rr) {
          const int kl = (rr & 3) + 8 * (rr >> 2);
          st[rr] = exp2f(kl > rhs ? -1e30f : st[rr]);
        }
      } else {
#pragma unroll
        for (int rr = 0; rr < 16; ++rr) st[rr] = exp2f(st[rr]);
      }
      union { unsigned u[4]; short8 s; } x, y;
      unsigned a0 = cvt_pk_bf16(st[0], st[1]), b0 = cvt_pk_bf16(st[4], st[5]);
      pl32swap(a0, b0);
      unsigned a1 = cvt_pk_bf16(st[2], st[3]), b1 = cvt_pk_bf16(st[6], st[7]);
      pl32swap(a1, b1);
      x.u[0] = a0; x.u[1] = a1; x.u[2] = b0; x.u[3] = b1; pf[2] = x.s;
      unsigned a2 = cvt_pk_bf16(st[8], st[9]), b2 = cvt_pk_bf16(st[12], st[13]);
      pl32swap(a2, b2);
      unsigned a3 = cvt_pk_bf16(st[10], st[11]), b3 = cvt_pk_bf16(st[14], st[15]);
      pl32swap(a3, b3);
      y.u[0] = a2; y.u[1] = a3; y.u[2] = b2; y.u[3] = b3; pf[3] = y.s;
    }
    __builtin_amdgcn_s_setprio(1);
#pragma unroll
    for (int dt = 0; dt < 2; ++dt) {
      const int row = dt * 32 + lane31;
      const int rx = (row & 7) << 4;
#pragma unroll
      for (int c = 0; c < 2; ++c) {
        const short8 vf = *reinterpret_cast<const short8*>(Vbuf + row * 128 + ((c * 32 + hi16) ^ rx));
        acc[dt] = __builtin_amdgcn_mfma_f32_32x32x16_bf16(pf[c], vf, acc[dt], 0, 0, 0);
      }
      if (do_hi) {
#pragma unroll
        for (int c = 2; c < 4; ++c) {
          const short8 vf = *reinterpret_cast<const short8*>(Vbuf + row * 128 + ((c * 32 + hi16) ^ rx));
          acc[dt] = __builtin_amdgcn_mfma_f32_32x32x16_bf16(pf[c], vf, acc[dt], 0, 0, 0);
        }
      }
    }
    accl = __builtin_amdgcn_mfma_f32_32x32x16_bf16(pf[0], ones8, accl, 0, 0, 0);
    accl = __builtin_amdgcn_mfma_f32_32x32x16_bf16(pf[1], ones8, accl, 0, 0, 0);
    if (do_hi) {
      accl = __builtin_amdgcn_mfma_f32_32x32x16_bf16(pf[2], ones8, accl, 0, 0, 0);
      accl = __builtin_amdgcn_mfma_f32_32x32x16_bf16(pf[3], ones8, accl, 0, 0, 0);
    }
    __builtin_amdgcn_s_setprio(0);
  }
  __syncthreads();
  unsigned short* Os = (unsigned short*)sm;
#pragma unroll
  for (int rr = 0; rr < 16; ++rr) {
    const int cr = (rr & 3) + 8 * (rr >> 2) + 4 * hi;
    const float inv = 1.f / accl[rr];
    const int row = wh * 32 + cr;
#pragma unroll
    for (int dt = 0; dt < 2; ++dt)
      Os[row * 128 + hl * 64 + dt * 32 + lane31] = f2bf(acc[dt][rr] * inv);
  }
  __syncthreads();
  unsigned short* Op = Ob + (size_t)(b * Sc + q0) * (HQc * 64) + (hk * 4 + hp * 2) * 64;
#pragma unroll
  for (int i = 0; i < 4; ++i) {
    const int cid = i * 256 + tid;
    const int row = cid >> 4;
    const int cb = (cid & 15) * 16;
    const uint4 v = *reinterpret_cast<const uint4*>(sm + row * 256 + cb);
    *reinterpret_cast<uint4*>((char*)(Op + (size_t)row * (HQc * 64)) + cb) = v;
  }
}

extern "C" void kernel_launch(void* const* d_in, const int* in_sizes, int n_in,
                              void* d_out, int out_size, void* d_ws, size_t ws_size,
                              hipStream_t stream) {
  (void)in_sizes; (void)n_in; (void)out_size; (void)ws_size;
  const float* x    = (const float*)d_in[0];
  const float* cosT = (const float*)d_in[1];
  const float* sinT = (const float*)d_in[2];
  // d_in[3] = mask: deterministic causal, not read
  const float* Wq = (const float*)d_in[4];
  const float* Wk = (const float*)d_in[5];
  const float* Wv = (const float*)d_in[6];
  const float* Wo = (const float*)d_in[7];
  float* out = (float*)d_out;
  char* ws = (char*)d_ws;
  const size_t MB = (size_t)1 << 20;
  unsigned short* xb   = (unsigned short*)(ws + 0 * MB);   // 16MB (x bf16; reused as Att)
  unsigned short* Wqkv = (unsigned short*)(ws + 16 * MB);  // 12MB [3072][2048]
  unsigned short* Wot  = (unsigned short*)(ws + 28 * MB);  // 8MB
  unsigned short* Kbf  = (unsigned short*)(ws + 36 * MB);  // 4MB
  unsigned short* Vtb  = (unsigned short*)(ws + 40 * MB);  // 4MB
  unsigned short* Att  = (unsigned short*)(ws + 0 * MB);   // reuse xb (dead after QKV GEMM)
  unsigned short* QKVp = (unsigned short*)d_out;           // 24MB in d_out (dead before O-proj)

  prep<<<10752, 256, 0, stream>>>(x, Wq, Wk, Wv, Wo, xb, Wqkv, Wot);
  gemm_qkv96<<<1024, 256, 0, stream>>>(xb, Wqkv, QKVp);
  post<<<4608, 256, 0, stream>>>(QKVp, cosT, sinT, Kbf, Vtb);
  attn_fwd<<<1024, 256, 0, stream>>>(QKVp, Kbf, Vtb, cosT, sinT, Att);
  gemm_o64<<<1024, 256, 0, stream>>>(Att, Wot, out);
}

// Round 21
// 187.238 us; speedup vs baseline: 1.0067x; 1.0008x over previous
//
#include <hip/hip_runtime.h>
#include <hip/hip_bf16.h>
#include <type_traits>

#define DEV __device__ __forceinline__

typedef __attribute__((ext_vector_type(4))) float f32x4;
typedef __attribute__((ext_vector_type(16))) float f32x16;
typedef __attribute__((ext_vector_type(8))) short short8;

static constexpr int Bc = 2, Sc = 2048, HQc = 32, HKVc = 8;

DEV unsigned short f2bf(float f) {
  union { float f; unsigned u; } v; v.f = f;
  unsigned r = v.u + 0x7fffu + ((v.u >> 16) & 1u);
  return (unsigned short)(r >> 16);
}
DEV float bf2f(unsigned short u) {
  union { unsigned u; float f; } v; v.u = ((unsigned)u) << 16;
  return v.f;
}

typedef const unsigned __attribute__((address_space(1)))* gp1;
typedef unsigned __attribute__((address_space(3)))* lp3;
DEV void gload16(const void* g, void* l) {
  __builtin_amdgcn_global_load_lds((gp1)g, (lp3)l, 16, 0, 0);
}

DEV unsigned cvt_pk_bf16(float lo, float hi) {
  unsigned r;
  asm("v_cvt_pk_bf16_f32 %0, %1, %2" : "=v"(r) : "v"(lo), "v"(hi));
  return r;
}
DEV void pl32swap(unsigned& a, unsigned& b) {
  asm("v_permlane32_swap_b32 %0, %1" : "+v"(a), "+v"(b));
}

// ---------------- prep: cast_x + 4x wtrans merged ----------------
__global__ __launch_bounds__(256) void prep(const float* __restrict__ x,
                                            const float* __restrict__ Wq,
                                            const float* __restrict__ Wk,
                                            const float* __restrict__ Wv,
                                            const float* __restrict__ Wo,
                                            unsigned short* __restrict__ xb,
                                            unsigned short* __restrict__ Wqkv,
                                            unsigned short* __restrict__ Wot) {
  __shared__ float t[64][65];
  const int bid = blockIdx.x;
  const int tid = threadIdx.x;
  if (bid < 8192) {
    const size_t i = (size_t)bid * 256 + tid;
    const float4 v = reinterpret_cast<const float4*>(x)[i];
    ushort4 o;
    o.x = f2bf(v.x); o.y = f2bf(v.y); o.z = f2bf(v.z); o.w = f2bf(v.w);
    reinterpret_cast<ushort4*>(xb)[i] = o;
    return;
  }
  const int tbl = bid - 8192;
  const float* in; unsigned short* out; int N, bx, by;
  if (tbl < 1024) { in = Wq; out = Wqkv; N = 2048; bx = tbl & 31; by = tbl >> 5; }
  else if (tbl < 1280) { const int t2 = tbl - 1024; in = Wk; out = Wqkv + (size_t)2048 * 2048; N = 512; bx = t2 & 7; by = t2 >> 3; }
  else if (tbl < 1536) { const int t2 = tbl - 1280; in = Wv; out = Wqkv + (size_t)2560 * 2048; N = 512; bx = t2 & 7; by = t2 >> 3; }
  else { const int t2 = tbl - 1536; in = Wo; out = Wot; N = 2048; bx = t2 & 31; by = t2 >> 5; }
  const int K = 2048;
  const int n0 = bx * 64, k0 = by * 64;
#pragma unroll
  for (int p = 0; p < 4; ++p) {
    const int kr = p * 16 + (tid >> 4);
    const int c = (tid & 15) * 4;
    const float4 v = *reinterpret_cast<const float4*>(&in[(size_t)(k0 + kr) * N + n0 + c]);
    t[c + 0][kr] = v.x; t[c + 1][kr] = v.y; t[c + 2][kr] = v.z; t[c + 3][kr] = v.w;
  }
  __syncthreads();
  const int n = tid >> 2, kc = (tid & 3) * 16;
  union { unsigned short u[16]; uint4 q[2]; } o;
#pragma unroll
  for (int e = 0; e < 16; ++e) o.u[e] = f2bf(t[n][kc + e]);
  uint4* dst = reinterpret_cast<uint4*>(&out[(size_t)(n0 + n) * K + k0 + kc]);
  dst[0] = o.q[0]; dst[1] = o.q[1];
}

// ---------------- QKV GEMM: 128x96 tiles -> 1024 wg = 4 blocks/CU ----------------
__global__ __launch_bounds__(256) void gemm_qkv96(const unsigned short* __restrict__ A,
                                                  const unsigned short* __restrict__ Bt,
                                                  unsigned short* __restrict__ C) {
  constexpr int K = 2048, N = 3072;
  int bid = blockIdx.x;
  { const int xcd = bid & 7, lid = bid >> 3; bid = xcd * 128 + lid; }  // 1024 % 8 == 0
  const int m0 = (bid >> 5) * 128, n0 = (bid & 31) * 96;
  __shared__ __align__(16) unsigned short As[128 * 64];  // 16KB
  __shared__ __align__(16) unsigned short Bs[96 * 64];   // 12KB
  const int tid = threadIdx.x;
  const int w = tid >> 6, lane = tid & 63;
  const int g = lane >> 4, lm = lane & 15;
  const int wr = w >> 1, wc = w & 1;     // wave tile: 64 rows x 48 cols
  f32x4 acc[4][3] = {};
  const char* Abase = (const char*)(A + (size_t)m0 * K);
  const char* Bbase = (const char*)(Bt + (size_t)n0 * K);
  const int offA = w * 4096 + 16 * lane;
  const int offB = w * 3072 + 16 * lane;
  for (int kt = 0; kt < 32; ++kt) {
    __syncthreads();
#pragma unroll
    for (int i = 0; i < 4; ++i) {
      const int o = offA + i * 1024;
      const int row = o >> 7;
      const int kbs = (o & 127) ^ ((row & 7) << 4);
      gload16(Abase + (size_t)row * (2 * K) + (size_t)kt * 128 + kbs,
              (char*)As + (w * 4096 + i * 1024));
    }
#pragma unroll
    for (int i = 0; i < 3; ++i) {
      const int o = offB + i * 1024;
      const int row = o >> 7;                       // 0..95
      const int kbs = (o & 127) ^ ((row & 7) << 4);
      gload16(Bbase + (size_t)row * (2 * K) + (size_t)kt * 128 + kbs,
              (char*)Bs + (w * 3072 + i * 1024));
    }
    __syncthreads();
#pragma unroll
    for (int ks = 0; ks < 2; ++ks) {
      short8 af[4], bfr[3];
#pragma unroll
      for (int i = 0; i < 4; ++i) {
        const int ar = wr * 64 + i * 16 + lm;
        af[i] = *reinterpret_cast<const short8*>((const char*)As + ar * 128 + (((ks * 4 + g) ^ (ar & 7)) << 4));
      }
#pragma unroll
      for (int j = 0; j < 3; ++j) {
        const int br = wc * 48 + j * 16 + lm;
        bfr[j] = *reinterpret_cast<const short8*>((const char*)Bs + br * 128 + (((ks * 4 + g) ^ (br & 7)) << 4));
      }
#pragma unroll
      for (int i = 0; i < 4; ++i)
#pragma unroll
        for (int j = 0; j < 3; ++j)
          acc[i][j] = __builtin_amdgcn_mfma_f32_16x16x32_bf16(af[i], bfr[j], acc[i][j], 0, 0, 0);
    }
  }
#pragma unroll
  for (int i = 0; i < 4; ++i)
#pragma unroll
    for (int j = 0; j < 3; ++j)
#pragma unroll
      for (int r = 0; r < 4; ++r) {
        const size_t idx = (size_t)(m0 + wr * 64 + i * 16 + g * 4 + r) * N + (n0 + wc * 48 + j * 16 + lm);
        C[idx] = f2bf(acc[i][j][r]);
      }
}

// ---------------- O-proj GEMM: 64x128 tiles -> 1024 wg = 4 blocks/CU ----------------
__global__ __launch_bounds__(256) void gemm_o64(const unsigned short* __restrict__ A,
                                                const unsigned short* __restrict__ Bt,
                                                float* __restrict__ C) {
  constexpr int K = 2048, N = 2048;
  int bid = blockIdx.x;
  { const int xcd = bid & 7, lid = bid >> 3; bid = xcd * 128 + lid; }  // 1024 % 8 == 0
  const int m0 = (bid >> 4) * 64, n0 = (bid & 15) * 128;
  __shared__ __align__(16) unsigned short As[64 * 64];    // 8KB
  __shared__ __align__(16) unsigned short Bs[128 * 64];   // 16KB
  const int tid = threadIdx.x;
  const int w = tid >> 6, lane = tid & 63;
  const int g = lane >> 4, lm = lane & 15;
  const int wr = w >> 1, wc = w & 1;     // wave tile: 32 rows x 64 cols
  f32x4 acc[2][4] = {};
  const char* Abase = (const char*)(A + (size_t)m0 * K);
  const char* Bbase = (const char*)(Bt + (size_t)n0 * K);
  for (int kt = 0; kt < 32; ++kt) {
    __syncthreads();
#pragma unroll
    for (int i = 0; i < 2; ++i) {
      const int o = i * 4096 + tid * 16;
      const int row = o >> 7;                       // 0..63
      const int kbs = (o & 127) ^ ((row & 7) << 4);
      gload16(Abase + (size_t)row * (2 * K) + (size_t)kt * 128 + kbs,
              (char*)As + (i * 4096 + w * 1024));
    }
#pragma unroll
    for (int i = 0; i < 4; ++i) {
      const int o = i * 4096 + tid * 16;
      const int row = o >> 7;                       // 0..127
      const int kbs = (o & 127) ^ ((row & 7) << 4);
      gload16(Bbase + (size_t)row * (2 * K) + (size_t)kt * 128 + kbs,
              (char*)Bs + (i * 4096 + w * 1024));
    }
    __syncthreads();
#pragma unroll
    for (int ks = 0; ks < 2; ++ks) {
      short8 af[2], bfr[4];
#pragma unroll
      for (int i = 0; i < 2; ++i) {
        const int ar = wr * 32 + i * 16 + lm;
        af[i] = *reinterpret_cast<const short8*>((const char*)As + ar * 128 + (((ks * 4 + g) ^ (ar & 7)) << 4));
      }
#pragma unroll
      for (int j = 0; j < 4; ++j) {
        const int br = wc * 64 + j * 16 + lm;
        bfr[j] = *reinterpret_cast<const short8*>((const char*)Bs + br * 128 + (((ks * 4 + g) ^ (br & 7)) << 4));
      }
#pragma unroll
      for (int i = 0; i < 2; ++i)
#pragma unroll
        for (int j = 0; j < 4; ++j)
          acc[i][j] = __builtin_amdgcn_mfma_f32_16x16x32_bf16(af[i], bfr[j], acc[i][j], 0, 0, 0);
    }
  }
#pragma unroll
  for (int i = 0; i < 2; ++i)
#pragma unroll
    for (int j = 0; j < 4; ++j)
#pragma unroll
      for (int r = 0; r < 4; ++r) {
        const size_t idx = (size_t)(m0 + wr * 32 + i * 16 + g * 4 + r) * N + (n0 + wc * 64 + j * 16 + lm);
        C[idx] = acc[i][j][r];
      }
}

// ---------------- post: ropeK + repack_v ----------------
DEV void rope_body(const unsigned short* __restrict__ Xp, const float* __restrict__ cosT,
                   const float* __restrict__ sinT, unsigned short* __restrict__ Xb,
                   int NH, int colOff, float qs, int bid, int tid) {
  const size_t i = (size_t)bid * 256 + tid;
  const int d = (int)(i & 31);
  const size_t t = i >> 5;
  const int h = (int)(t % NH);
  const size_t row = t / NH;
  const int s = (int)(row & (Sc - 1));
  const size_t b = row >> 11;
  const size_t ib = row * 3072 + colOff + (size_t)h * 64 + d;
  const float q1 = bf2f(Xp[ib]);
  const float q2 = bf2f(Xp[ib + 32]);
  const float c = cosT[s * 64 + d], sn = sinT[s * 64 + d];
  const size_t ob = ((b * NH + h) * (size_t)Sc + s) * 64 + d;
  Xb[ob] = f2bf((q1 * c - q2 * sn) * qs);
  Xb[ob + 32] = f2bf((q2 * c + q1 * sn) * qs);
}

__global__ __launch_bounds__(256) void post(const unsigned short* __restrict__ QKVp,
                                            const float* __restrict__ cosT,
                                            const float* __restrict__ sinT,
                                            unsigned short* __restrict__ Kbf,
                                            unsigned short* __restrict__ Vtb) {
  __shared__ int t[64][65];
  const int bid = blockIdx.x;
  const int tid = threadIdx.x;
  if (bid < 4096) {
    rope_body(QKVp, cosT, sinT, Kbf, HKVc, 2048, 1.0f, bid, tid);
    return;
  }
  const int tv = bid - 4096;
  const int bh = tv >> 5;
  const int s0 = (tv & 31) * 64;
  const int b = bh >> 3, hk = bh & 7;
#pragma unroll
  for (int p = 0; p < 2; ++p) {
    const int sr = p * 32 + (tid >> 3);
    const int c = (tid & 7) * 8;
    short8 v = *reinterpret_cast<const short8*>(&QKVp[(size_t)(b * Sc + s0 + sr) * 3072 + 2560 + hk * 64 + c]);
#pragma unroll
    for (int e = 0; e < 8; ++e) t[c + e][sr] = (unsigned short)v[e];
  }
  __syncthreads();
  const int d = tid >> 2, scol = (tid & 3) * 16;
  union { unsigned short u[16]; uint4 q[2]; } o;
#pragma unroll
  for (int e = 0; e < 16; ++e) o.u[e] = (unsigned short)t[d][scol + e];
  uint4* dst = reinterpret_cast<uint4*>(&Vtb[((size_t)bh * 64 + d) * Sc + s0 + scol]);
  dst[0] = o.q[0]; dst[1] = o.q[1];
}

// ---------------- causal GQA flash attention: r20 + fused QK clusters (within-wave MFMA/exp ILP) ----
// Both S^T tiles' MFMAs issue back-to-back before the trans-pipe exp chains, so the
// matrix pipe drains under the exp of tile0 instead of serializing in two chunks.
__global__ __launch_bounds__(256, 4) void attn_fwd(const unsigned short* __restrict__ QKVp,
                                                   const unsigned short* __restrict__ Kb,
                                                   const unsigned short* __restrict__ Vt,
                                                   const float* __restrict__ cosT,
                                                   const float* __restrict__ sinT,
                                                   unsigned short* __restrict__ Ob) {
  __shared__ __align__(16) char sm[32768];
  const int tid = threadIdx.x;
  const int w = tid >> 6, lane = tid & 63;
  const int lane31 = lane & 31, hi = lane >> 5;
  const int hi16 = hi * 16;
  const int hl = w >> 1, wh = w & 1;
  const int bid = blockIdx.x;
  const int hk = bid & 7;
  const int sub = (bid >> 3) & 3;
  const int tq = (bid >> 5) & 7;
  const int quarter = bid >> 8;
  int qt;
  if (quarter == 0) qt = 31 - tq;
  else if (quarter == 1) qt = 16 + tq;
  else if (quarter == 2) qt = 15 - tq;
  else qt = tq;
  const int b = sub >> 1, hp = sub & 1;
  const int h = hk * 4 + hp * 2 + hl;
  const int q0 = qt * 64;
  const char* Kbase = (const char*)(Kb + (size_t)(b * HKVc + hk) * Sc * 64);
  const char* Vbase = (const char*)(Vt + (size_t)(b * HKVc + hk) * 64 * Sc);
  const int srow = q0 + wh * 32 + lane31;
  const unsigned short* Qraw = QKVp + ((size_t)(b * Sc) + srow) * 3072 + h * 64;
  short8 qraw[4];
#pragma unroll
  for (int c = 0; c < 4; ++c)
    qraw[c] = *reinterpret_cast<const short8*>(Qraw + c * 16 + hi * 8);
  const float* cbp = cosT + (size_t)srow * 64;
  const float* sbp = sinT + (size_t)srow * 64;
  const float qs = 0.125f * 1.44269504089f;
  short8 qf[4];
#pragma unroll
  for (int c = 0; c < 4; ++c) {
    short8 o;
#pragma unroll
    for (int e = 0; e < 8; ++e) {
      const int d = c * 16 + hi * 8 + e;
      const float v = bf2f((unsigned short)qraw[c][e]);
      const float p = bf2f((unsigned short)qraw[c ^ 2][e]);
      const float sgn = (d < 32) ? -1.f : 1.f;
      o[e] = (short)f2bf((v * cbp[d] + sgn * p * sbp[d]) * qs);
    }
    qf[c] = o;
  }

  f32x16 acc[2] = {};
  f32x16 accl = {};
  const int qlocal = wh * 32 + lane31 - 4 * hi;
  union { unsigned u[4]; short8 s; } onesu;
  onesu.u[0] = onesu.u[1] = onesu.u[2] = onesu.u[3] = 0x3f803f80u;
  const short8 ones8 = onesu.s;

  const int so0 = tid * 16;
  auto stage = [&](int kt, int buf) {
    char* Kd = sm + buf * 16384;
    char* Vd = sm + buf * 16384 + 8192;
#pragma unroll
    for (int q = 0; q < 2; ++q) {
      const int o = q * 4096 + so0;
      const int srw = o >> 7;
      const int kbs = (o & 127) ^ ((srw & 7) << 4);
      const int ld = q * 4096 + w * 1024;
      gload16(Kbase + (size_t)(kt * 64 + srw) * 128 + kbs, Kd + ld);
      gload16(Vbase + (size_t)srw * (Sc * 2) + (size_t)kt * 128 + kbs, Vd + ld);
    }
  };

  stage(0, 0);
  for (int kt = 0; kt <= qt; ++kt) {
    const int cur = kt & 1;
    __builtin_amdgcn_s_barrier();
    if (kt < qt) {
      stage(kt + 1, cur ^ 1);
      asm volatile("s_waitcnt vmcnt(4)" ::: "memory");
    } else {
      asm volatile("s_waitcnt vmcnt(0)" ::: "memory");
    }
    __builtin_amdgcn_sched_barrier(0);
    __builtin_amdgcn_s_barrier();
    const char* Kbuf = sm + cur * 16384;
    const char* Vbuf = sm + cur * 16384 + 8192;
    const bool dg = (kt == qt);
    const bool do_hi = !dg || (wh == 1);
    short8 pf[4];
    // ---- both QK^T clusters back-to-back (matrix pipe fills, drains under exp) ----
    f32x16 st0 = {}, st1 = {};
    __builtin_amdgcn_s_setprio(1);
#pragma unroll
    for (int c = 0; c < 4; ++c) {
      const int row = lane31;
      const short8 kf = *reinterpret_cast<const short8*>(Kbuf + row * 128 + ((c * 32 + hi16) ^ ((row & 7) << 4)));
      st0 = __builtin_amdgcn_mfma_f32_32x32x16_bf16(kf, qf[c], st0, 0, 0, 0);
    }
    if (do_hi) {
#pragma unroll
      for (int c = 0; c < 4; ++c) {
        const int row = 32 + lane31;
        const short8 kf = *reinterpret_cast<const short8*>(Kbuf + row * 128 + ((c * 32 + hi16) ^ ((row & 7) << 4)));
        st1 = __builtin_amdgcn_mfma_f32_32x32x16_bf16(kf, qf[c], st1, 0, 0, 0);
      }
    }
    __builtin_amdgcn_s_setprio(0);
    // ---- exp + pack tile0 ----
    {
      if (dg && wh == 0) {
#pragma unroll
        for (int rr = 0; rr < 16; ++rr) {
          const int kl = (rr & 3) + 8 * (rr >> 2);
          st0[rr] = exp2f(kl > qlocal ? -1e30f : st0[rr]);
        }
      } else {
#pragma unroll
        for (int rr = 0; rr < 16; ++rr) st0[rr] = exp2f(st0[rr]);
      }
      union { unsigned u[4]; short8 s; } x, y;
      unsigned a0 = cvt_pk_bf16(st0[0], st0[1]), b0 = cvt_pk_bf16(st0[4], st0[5]);
      pl32swap(a0, b0);
      unsigned a1 = cvt_pk_bf16(st0[2], st0[3]), b1 = cvt_pk_bf16(st0[6], st0[7]);
      pl32swap(a1, b1);
      x.u[0] = a0; x.u[1] = a1; x.u[2] = b0; x.u[3] = b1; pf[0] = x.s;
      unsigned a2 = cvt_pk_bf16(st0[8], st0[9]), b2 = cvt_pk_bf16(st0[12], st0[13]);
      pl32swap(a2, b2);
      unsigned a3 = cvt_pk_bf16(st0[10], st0[11]), b3 = cvt_pk_bf16(st0[14], st0[15]);
      pl32swap(a3, b3);
      y.u[0] = a2; y.u[1] = a3; y.u[2] = b2; y.u[3] = b3; pf[1] = y.s;
    }
    // ---- exp + pack tile1 ----
    if (do_hi) {
      if (dg) {
        const int rhs = qlocal - 32;
#pragma unroll
        for (int rr = 0; rr < 16; ++rr) {
          const int kl = (rr & 3) + 8 * (rr >> 2);
          st1[rr] = exp2f(kl > rhs ? -1e30f : st1[rr]);
        }
      } else {
#pragma unroll
        for (int rr = 0; rr < 16; ++rr) st1[rr] = exp2f(st1[rr]);
      }
      union { unsigned u[4]; short8 s; } x, y;
      unsigned a0 = cvt_pk_bf16(st1[0], st1[1]), b0 = cvt_pk_bf16(st1[4], st1[5]);
      pl32swap(a0, b0);
      unsigned a1 = cvt_pk_bf16(st1[2], st1[3]), b1 = cvt_pk_bf16(st1[6], st1[7]);
      pl32swap(a1, b1);
      x.u[0] = a0; x.u[1] = a1; x.u[2] = b0; x.u[3] = b1; pf[2] = x.s;
      unsigned a2 = cvt_pk_bf16(st1[8], st1[9]), b2 = cvt_pk_bf16(st1[12], st1[13]);
      pl32swap(a2, b2);
      unsigned a3 = cvt_pk_bf16(st1[10], st1[11]), b3 = cvt_pk_bf16(st1[14], st1[15]);
      pl32swap(a3, b3);
      y.u[0] = a2; y.u[1] = a3; y.u[2] = b2; y.u[3] = b3; pf[3] = y.s;
    }
    // ---- PV + row-sum ----
    __builtin_amdgcn_s_setprio(1);
#pragma unroll
    for (int dt = 0; dt < 2; ++dt) {
      const int row = dt * 32 + lane31;
      const int rx = (row & 7) << 4;
#pragma unroll
      for (int c = 0; c < 2; ++c) {
        const short8 vf = *reinterpret_cast<const short8*>(Vbuf + row * 128 + ((c * 32 + hi16) ^ rx));
        acc[dt] = __builtin_amdgcn_mfma_f32_32x32x16_bf16(pf[c], vf, acc[dt], 0, 0, 0);
      }
      if (do_hi) {
#pragma unroll
        for (int c = 2; c < 4; ++c) {
          const short8 vf = *reinterpret_cast<const short8*>(Vbuf + row * 128 + ((c * 32 + hi16) ^ rx));
          acc[dt] = __builtin_amdgcn_mfma_f32_32x32x16_bf16(pf[c], vf, acc[dt], 0, 0, 0);
        }
      }
    }
    accl = __builtin_amdgcn_mfma_f32_32x32x16_bf16(pf[0], ones8, accl, 0, 0, 0);
    accl = __builtin_amdgcn_mfma_f32_32x32x16_bf16(pf[1], ones8, accl, 0, 0, 0);
    if (do_hi) {
      accl = __builtin_amdgcn_mfma_f32_32x32x16_bf16(pf[2], ones8, accl, 0, 0, 0);
      accl = __builtin_amdgcn_mfma_f32_32x32x16_bf16(pf[3], ones8, accl, 0, 0, 0);
    }
    __builtin_amdgcn_s_setprio(0);
  }
  __syncthreads();
  unsigned short* Os = (unsigned short*)sm;
#pragma unroll
  for (int rr = 0; rr < 16; ++rr) {
    const int cr = (rr & 3) + 8 * (rr >> 2) + 4 * hi;
    const float inv = 1.f / accl[rr];
    const int row = wh * 32 + cr;
#pragma unroll
    for (int dt = 0; dt < 2; ++dt)
      Os[row * 128 + hl * 64 + dt * 32 + lane31] = f2bf(acc[dt][rr] * inv);
  }
  __syncthreads();
  unsigned short* Op = Ob + (size_t)(b * Sc + q0) * (HQc * 64) + (hk * 4 + hp * 2) * 64;
#pragma unroll
  for (int i = 0; i < 4; ++i) {
    const int cid = i * 256 + tid;
    const int row = cid >> 4;
    const int cb = (cid & 15) * 16;
    const uint4 v = *reinterpret_cast<const uint4*>(sm + row * 256 + cb);
    *reinterpret_cast<uint4*>((char*)(Op + (size_t)row * (HQc * 64)) + cb) = v;
  }
}

extern "C" void kernel_launch(void* const* d_in, const int* in_sizes, int n_in,
                              void* d_out, int out_size, void* d_ws, size_t ws_size,
                              hipStream_t stream) {
  (void)in_sizes; (void)n_in; (void)out_size; (void)ws_size;
  const float* x    = (const float*)d_in[0];
  const float* cosT = (const float*)d_in[1];
  const float* sinT = (const float*)d_in[2];
  // d_in[3] = mask: deterministic causal, not read
  const float* Wq = (const float*)d_in[4];
  const float* Wk = (const float*)d_in[5];
  const float* Wv = (const float*)d_in[6];
  const float* Wo = (const float*)d_in[7];
  float* out = (float*)d_out;
  char* ws = (char*)d_ws;
  const size_t MB = (size_t)1 << 20;
  unsigned short* xb   = (unsigned short*)(ws + 0 * MB);   // 16MB (x bf16; reused as Att)
  unsigned short* Wqkv = (unsigned short*)(ws + 16 * MB);  // 12MB [3072][2048]
  unsigned short* Wot  = (unsigned short*)(ws + 28 * MB);  // 8MB
  unsigned short* Kbf  = (unsigned short*)(ws + 36 * MB);  // 4MB
  unsigned short* Vtb  = (unsigned short*)(ws + 40 * MB);  // 4MB
  unsigned short* Att  = (unsigned short*)(ws + 0 * MB);   // reuse xb (dead after QKV GEMM)
  unsigned short* QKVp = (unsigned short*)d_out;           // 24MB in d_out (dead before O-proj)

  prep<<<10752, 256, 0, stream>>>(x, Wq, Wk, Wv, Wo, xb, Wqkv, Wot);
  gemm_qkv96<<<1024, 256, 0, stream>>>(xb, Wqkv, QKVp);
  post<<<4608, 256, 0, stream>>>(QKVp, cosT, sinT, Kbf, Vtb);
  attn_fwd<<<1024, 256, 0, stream>>>(QKVp, Kbf, Vtb, cosT, sinT, Att);
  gemm_o64<<<1024, 256, 0, stream>>>(Att, Wot, out);
}